// Round 8
// baseline (37.564 us; speedup 1.0000x reference)
//
#include <hip/hip_runtime.h>

#define GRIDD  76                 // grid dim (H = W)
#define NROWS  255                // anchors(3) * attrs(85)
#define GG     (GRIDD * GRIDD)    // 5776
#define HROWS  64                 // rem rows per half
#define UPITCH 76                 // dwords, ZERO pad: linear slab; gll16-compatible,
                                  // phase-2 lane stride 19 quads (3 mod 8) -> conflict-free
#define UDW    (2 * HROWS * UPITCH)   // 9728 dwords = 38912 B -> 4 blocks/CU

typedef __attribute__((address_space(3))) unsigned lds_u32;
typedef __attribute__((address_space(1))) unsigned glb_u32;

__device__ __forceinline__ void gll16(const float* g, float* l) {
    // async global->LDS, 16B/lane; LDS dest = wave-uniform base + lane*16
    __builtin_amdgcn_global_load_lds((const glb_u32*)g, (lds_u32*)l, 16, 0, 0);
}

// Stage one 64-row half (1216 float4 quads). Exactly 3 gll16 per wave (uniform),
// so a counted s_waitcnt vmcnt(N) is the same for every wave.
__device__ __forceinline__ void stage_half(const float* __restrict__ src,
                                           float* dstbase,
                                           unsigned wid, unsigned lane)
{
    #pragma unroll
    for (unsigned k = 0; k < 2u; ++k) {
        unsigned i   = k * 512u + (wid << 6) + lane;   // quad 0..1023
        unsigned row = i / 19u;
        unsigned qc  = i - row * 19u;
        gll16(src + (size_t)row * GG + (qc << 2),
              dstbase + (size_t)(k * 512u + (wid << 6)) * 4u);
    }
    {   // tail 192 quads: 24 per wave, lanes 0..23
        unsigned i = 1024u + wid * 24u + lane;
        if (lane < 24u) {
            unsigned row = i / 19u;
            unsigned qc  = i - row * 19u;
            gll16(src + (size_t)row * GG + (qc << 2),
                  dstbase + (size_t)(1024u + wid * 24u) * 4u);
        }
    }
}

// Transform + transposed store for one 64-row half. lane = slab row.
__device__ __forceinline__ void compute_half(const float* __restrict__ bc,
                                             float* __restrict__ outbh,
                                             unsigned remBase, unsigned lane,
                                             unsigned wid, float stride, float fh)
{
    const unsigned rem  = remBase + lane;              // 0..254
    const unsigned a    = (rem >= 170u) ? 2u : ((rem >= 85u) ? 1u : 0u);
    const unsigned attr = rem - a * 85u;
    const bool  wh  = (attr == 2u) | (attr == 3u);
    const bool  isx = (attr == 0u);
    float anc = 0.f;
    if (attr == 2u) anc = (a == 0u) ? 12.f : ((a == 1u) ? 19.f : 40.f);
    if (attr == 3u) anc = (a == 0u) ? 16.f : ((a == 1u) ? 36.f : 28.f);
    const float mB    = -0.1f * stride;
    const float slog  = wh ? 1.44269504f : -1.44269504f;   // +-log2(e), premultiplied
    const float A2    = wh ? anc : ((attr < 2u) ? 1.2f * stride : 1.f);
    const float wsel  = isx ? stride : 0.f;
    const float basef = (attr == 1u) ? fmaf(fh, stride, mB) : (isx ? mB : 0.f);
    float* __restrict__ dst = outbh + rem;

    #pragma unroll
    for (unsigned j = 0; j < 3u; ++j) {
        const unsigned tt = wid + (j << 3);            // quad col 0..18
        if (tt < 19u) {
            // lane stride 76 dwords = 19 quads (3 mod 8) -> conflict-free b128
            const float4 vv = *reinterpret_cast<const float4*>(
                bc + (size_t)lane * UPITCH + (tt << 2));
            #pragma unroll
            for (unsigned i = 0; i < 4u; ++i) {
                const float v  = (i == 0) ? vv.x : (i == 1) ? vv.y : (i == 2) ? vv.z : vv.w;
                const float uf = (float)((tt << 2) + i);
                const float e2 = exp2f(v * slog);      // v_mul + v_exp
                const float sg = __builtin_amdgcn_rcpf(1.0f + e2);
                const float q  = wh ? e2 : sg;         // cndmask (lane-const pred)
                const float o  = fmaf(q, A2, fmaf(uf, wsel, basef));
                dst[(size_t)((tt << 2) + i) * NROWS] = o;   // 64-rem 256B runs
            }
        }
    }
}

__global__ __launch_bounds__(512, 8) void yolo_head_kernel(
    const float* __restrict__ x, const int* __restrict__ dimp,
    float* __restrict__ out)
{
    __shared__ float buf[UDW];
    // XCD-bijective swizzle (2432 = 8*304): both halves of a rem column and
    // neighboring h share one XCD L2 -> seam cache-lines merge (proven r4/r6).
    const unsigned lb    = (blockIdx.x & 7u) * 304u + (blockIdx.x >> 3);
    const unsigned b     = lb / 152u;
    const unsigned hr    = lb - b * 152u;
    const unsigned h     = hr >> 1;
    const unsigned rbase = (hr & 1u) * 127u;    // unit rows rbase..rbase+127
    const unsigned t     = threadIdx.x;
    const unsigned wid   = t >> 6;
    const unsigned lane  = t & 63u;
    const float stride   = (float)(*dimp / GRIDD);   // 608/76 = 8
    const float fh       = (float)h;

    // ---- issue BOTH halves' loads up front (6 gll16/wave, in order) ----
    const float* __restrict__ src0 = x + (size_t)(b * NROWS + rbase) * GG + h * GRIDD;
    stage_half(src0,                        buf,                  wid, lane);
    stage_half(src0 + (size_t)HROWS * GG,   buf + HROWS * UPITCH, wid, lane);

    // half-0 ready: wait for this wave's first 3 loads (vmcnt is in-order),
    // then block barrier so all waves' half-0 quads are visible.
    asm volatile("s_waitcnt vmcnt(3)\n\ts_barrier" ::: "memory");

    float* __restrict__ outbh = out + (size_t)(b * GRIDD + h) * (GRIDD * NROWS);
    compute_half(buf, outbh, rbase, lane, wid, stride, fh);        // half-1 loads fly under this

    __syncthreads();   // drains remaining vmcnt -> half-1 slab ready
    compute_half(buf + HROWS * UPITCH, outbh, rbase + HROWS, lane, wid, stride, fh);
}

extern "C" void kernel_launch(void* const* d_in, const int* in_sizes, int n_in,
                              void* d_out, int out_size, void* d_ws, size_t ws_size,
                              hipStream_t stream) {
    const float* x  = (const float*)d_in[0];
    const int* dimp = (const int*)d_in[1];
    float* out      = (float*)d_out;
    const int B = in_sizes[0] / (NROWS * GG);   // 16
    yolo_head_kernel<<<B * GRIDD * 2, 512, 0, stream>>>(x, dimp, out);
}

// Round 9
// 32.958 us; speedup vs baseline: 1.1398x; 1.1398x over previous
//
#include <hip/hip_runtime.h>

#define GRIDD  76                 // grid dim (H = W)
#define NROWS  255                // anchors(3) * attrs(85)
#define GG     (GRIDD * GRIDD)    // 5776
#define QROWS  64                 // rem rows per block (quarter unit)
#define QQ     (QROWS * 19)       // 1216 float4 quads per slab
#define QDW    (QROWS * GRIDD)    // 4864 dwords = 19456 B -> 8 blocks/CU

typedef __attribute__((address_space(3))) unsigned lds_u32;
typedef __attribute__((address_space(1))) unsigned glb_u32;

__device__ __forceinline__ void gll16(const float* g, float* l) {
    // async global->LDS, 16B/lane; LDS dest = wave-uniform base + lane*16
    __builtin_amdgcn_global_load_lds((const glb_u32*)g, (lds_u32*)l, 16, 0, 0);
}

__global__ __launch_bounds__(256, 8) void yolo_head_kernel(
    const float* __restrict__ x, const int* __restrict__ dimp,
    float* __restrict__ out)
{
    __shared__ float buf[QDW];    // zero-pad [64][76] slab, linear = gll16-compatible
    // XCD-bijective swizzle (4864 = 8*608): the 4 quarters of a (b,h) and
    // neighboring h stay on ONE XCD L2 and launch adjacently -> quarter-seam
    // cache lines merge before HBM writeback (r4/r6-proven pattern).
    const unsigned lb    = (blockIdx.x & 7u) * 608u + (blockIdx.x >> 3);
    const unsigned b     = lb / 304u;
    const unsigned hq    = lb - b * 304u;
    const unsigned h     = hq >> 2;
    const unsigned q     = hq & 3u;
    const unsigned rbase = (q == 3u) ? 191u : (q << 6);  // q3 overlaps row 191 (idempotent)
    const unsigned t     = threadIdx.x;
    const unsigned wid   = t >> 6;
    const unsigned lane  = t & 63u;
    const float stride   = (float)(*dimp / GRIDD);       // 608/76 = 8
    const float fh       = (float)h;

    // ---- phase 1: async-stage [64 rem][76 w], linear LDS dest ----
    const float* __restrict__ src = x + (size_t)(b * NROWS + rbase) * GG + h * GRIDD;
    #pragma unroll
    for (unsigned k = 0; k < 5u; ++k) {
        unsigned i = k * 256u + (wid << 6) + lane;       // quad 0..1215
        if (i < QQ) {                                    // k=4: waves 0-2 (uniform)
            unsigned row = i / 19u;
            unsigned qc  = i - row * 19u;
            gll16(src + (size_t)row * GG + (qc << 2),
                  buf + (size_t)(k * 256u + (wid << 6)) * 4u);  // +lane*16B implicit
        }
    }
    __syncthreads();                                     // drains vmcnt -> slab ready

    // ---- phase 2: lane = slab row; all attr logic lane-fixed, hoisted ----
    const unsigned rem  = rbase + lane;                  // 0..254
    const unsigned a    = (rem >= 170u) ? 2u : ((rem >= 85u) ? 1u : 0u);
    const unsigned attr = rem - a * 85u;
    const bool  wh  = (attr == 2u) | (attr == 3u);
    const bool  isx = (attr == 0u);
    float anc = 0.f;
    if (attr == 2u) anc = (a == 0u) ? 12.f : ((a == 1u) ? 19.f : 40.f);
    if (attr == 3u) anc = (a == 0u) ? 16.f : ((a == 1u) ? 36.f : 28.f);
    const float mB    = -0.1f * stride;
    const float slog  = wh ? 1.44269504f : -1.44269504f; // +-log2(e) premultiplied
    const float A2    = wh ? anc : ((attr < 2u) ? 1.2f * stride : 1.f);
    const float wsel  = isx ? stride : 0.f;
    const float basef = (attr == 1u) ? fmaf(fh, stride, mB) : (isx ? mB : 0.f);
    float* __restrict__ dst = out + (size_t)(b * GRIDD + h) * (GRIDD * NROWS) + rem;

    #pragma unroll
    for (unsigned j = 0; j < 5u; ++j) {
        const unsigned tt = wid + (j << 2);              // quad col 0..18
        if (tt < 19u) {                                  // j=4: waves 0-2 (uniform)
            // lane stride 19 quads (3 mod 8) -> uniform bank-quad spread, 0 conflicts
            const float4 vv = *reinterpret_cast<const float4*>(
                buf + (size_t)lane * GRIDD + (tt << 2));
            #pragma unroll
            for (unsigned i = 0; i < 4u; ++i) {
                const float v  = (i == 0) ? vv.x : (i == 1) ? vv.y : (i == 2) ? vv.z : vv.w;
                const float uf = (float)((tt << 2) + i);
                const float e2 = exp2f(v * slog);        // v_mul + v_exp
                const float sg = __builtin_amdgcn_rcpf(1.0f + e2);
                const float qv = wh ? e2 : sg;           // lane-const cndmask
                const float o  = fmaf(qv, A2, fmaf(uf, wsel, basef));
                dst[(size_t)((tt << 2) + i) * NROWS] = o;   // 64-rem 256B runs
            }
        }
    }
}

extern "C" void kernel_launch(void* const* d_in, const int* in_sizes, int n_in,
                              void* d_out, int out_size, void* d_ws, size_t ws_size,
                              hipStream_t stream) {
    const float* x  = (const float*)d_in[0];
    const int* dimp = (const int*)d_in[1];
    float* out      = (float*)d_out;
    const int B = in_sizes[0] / (NROWS * GG);   // 16
    yolo_head_kernel<<<B * GRIDD * 4, 256, 0, stream>>>(x, dimp, out);
}